// Round 1
// baseline (58.304 us; speedup 1.0000x reference)
//
#include <hip/hip_runtime.h>

// Patch Embed Outer Rotate:
//   x: (B=256, C=3, Hi=224, Wi=224) fp32, P=16 patches, h=w=14.
//   Per patch (wj, hk): transpose 16x16 patch unless wj in (w/3, 2w/3) AND hk in (h/3, 2h/3).
//   out[b,c, hk*16+p1, wj*16+p2] = transpose ? in[b,c, hk*16+p2, wj*16+p1]
//                                            : in[b,c, hk*16+p1, wj*16+p2]
// Pure data movement; memory-bound. One wave per patch, 4 patches per block.

constexpr int PS = 16;       // patch size
constexpr int LP = 17;       // LDS pitch (pad +1 to kill bank conflicts)

__global__ __launch_bounds__(256) void patch_rot_kernel(
    const float* __restrict__ in, float* __restrict__ out,
    int h, int w, int Wi) {
  __shared__ float lds[4][PS * LP];

  const int wave = threadIdx.x >> 6;
  const int lane = threadIdx.x & 63;
  const int pid  = blockIdx.x * 4 + wave;   // global patch index

  // decompose patch index: wj fastest, then hk, then (b*C + c)
  const int wj = pid % w;
  const int t1 = pid / w;
  const int hk = t1 % h;
  const int bc = t1 / h;

  const long plane = (long)bc * (long)(h * PS) * (long)Wi;

  const int i  = lane >> 2;          // row within patch, 0..15
  const int j4 = (lane & 3) << 2;    // col start within patch, {0,4,8,12}

  const long off = plane + (long)(hk * PS + i) * Wi + (long)(wj * PS + j4);

  // coalesced float4 load: each patch row = one aligned 64B line
  const float4 v = *reinterpret_cast<const float4*>(in + off);

  // inner (non-transposed) region: integer-exact form of  j > w/3 && j < 2w/3
  const bool inner = (3 * wj > w) && (3 * wj < 2 * w) &&
                     (3 * hk > h) && (3 * hk < 2 * h);

  float* L = lds[wave];
  L[i * LP + j4 + 0] = v.x;
  L[i * LP + j4 + 1] = v.y;
  L[i * LP + j4 + 2] = v.z;
  L[i * LP + j4 + 3] = v.w;
  __syncthreads();

  float4 o;
  if (!inner) {
    // transposed patch: out(p1=i, p2=j4+k) = in-patch(row j4+k, col i)
    o.x = L[(j4 + 0) * LP + i];
    o.y = L[(j4 + 1) * LP + i];
    o.z = L[(j4 + 2) * LP + i];
    o.w = L[(j4 + 3) * LP + i];
  } else {
    o = v;
  }

  // same (coalesced) layout as the load
  *reinterpret_cast<float4*>(out + off) = o;
}

extern "C" void kernel_launch(void* const* d_in, const int* in_sizes, int n_in,
                              void* d_out, int out_size, void* d_ws, size_t ws_size,
                              hipStream_t stream) {
  const float* in = (const float*)d_in[0];
  float* out = (float*)d_out;

  // shapes fixed by reference setup_inputs(): (256, 3, 224, 224), P=16
  const int B = 256, C = 3, Hi = 224, Wi = 224;
  const int h = Hi / PS;   // 14
  const int w = Wi / PS;   // 14

  const int npatch = B * C * h * w;        // 150,528
  const int nblocks = npatch / 4;          // 37,632 (divisible: 150528 = 4*37632)

  patch_rot_kernel<<<nblocks, 256, 0, stream>>>(in, out, h, w, Wi);
}